// Round 6
// baseline (580.124 us; speedup 1.0000x reference)
//
#include <hip/hip_runtime.h>

typedef float    f32x4 __attribute__((ext_vector_type(4)));
typedef _Float16 f16x4 __attribute__((ext_vector_type(4)));
typedef _Float16 f16x8 __attribute__((ext_vector_type(8)));

// direct global->LDS DMA, 16B per lane. LDS dest is wave-uniform base;
// HW writes lane l at (ldsbase + l*16). Global src is per-lane.
__device__ __forceinline__ void gload16(const void* g, void* l) {
  __builtin_amdgcn_global_load_lds(
      (const __attribute__((address_space(1))) void*)g,
      (__attribute__((address_space(3))) void*)l, 16, 0, 0);
}

#define MFMA16(d, a, b) __builtin_amdgcn_mfma_f32_16x16x32_f16(a, b, d, 0, 0, 0)
#define VMCNT(n) asm volatile("s_waitcnt vmcnt(" #n ")" ::: "memory")
#define LGKM0()  asm volatile("s_waitcnt lgkmcnt(0)" ::: "memory")
#define SB0()    __builtin_amdgcn_sched_barrier(0)
#define BAR()    __builtin_amdgcn_s_barrier()

#define G_LO(af, bf)                                  \
  _Pragma("unroll") for (int m_ = 0; m_ < 4; m_++)    \
  _Pragma("unroll") for (int n_ = 0; n_ < 4; n_++)    \
      acc[m_][n_] = MFMA16(acc[m_][n_], af[m_], bf[n_]);
#define G_HI(af, bf)                                  \
  _Pragma("unroll") for (int m_ = 0; m_ < 4; m_++)    \
  _Pragma("unroll") for (int n_ = 0; n_ < 4; n_++)    \
      acc[4 + m_][n_] = MFMA16(acc[4 + m_][n_], af[m_], bf[n_]);

// ---------------------------------------------------------------------------
// 256x256 fp16 GEMM, C = A * B^T (+bias)(+mask), fp32 accum, m201-style
// 4-phase pipelined schedule.  512 thr = 8 waves (2M x 4N), per-wave C =
// 128x64, acc[8][4] f32x4.  BK=64 as 2 K-halves of 32; LDS = 2 dbuf x {A,B}
// x 2 khalf x 16KB = 128 KiB.  Per K-half: [256 rows][32 halfs] (64B rows),
// XOR swizzle col ^= ((row>>1)&3)<<4 via pre-swizzled global src (linear DMA
// dst) + swizzled ds_read col (verified conflicts = 0, round 3).
//
// Phase structure (m201 template): { ds_reads ; stage 1 half-tile (2 gloads);
//   vmcnt(6); s_barrier; lgkmcnt(0)+sched_barrier(0); setprio(1); 16 MFMA;
//   setprio(0); s_barrier; sched_barrier(0) }.
// vmcnt(6) = 2 loads x 3 half-tiles in flight; never 0 in the main loop.
//
// Per tile t (buf d=t&1): stage order [B-K0,A-K0,A-K1,B-K1](t+1)->buf[d^1];
// MFMA: P0=Q3(t-1: m0-3,kk1), P1=Q4(t-1: m4-7,kk1)  (from buf[d^1]),
//       P2=Q1(t:   m0-3,kk0), P3=Q2(t:   m4-7,kk0)  (from buf[d]).
// Every read is >=4 phases after its stage (retired by the per-phase
// vmcnt(6) chain, published by the following barrier); every DMA overwrite
// is region-disjoint from concurrent readers (checked half-by-half).
// Per-element accumulation order (tiles asc, kk0 then kk1) is unchanged
// from the previous passing kernel -> bit-identical C.
// ---------------------------------------------------------------------------
template <typename TOUT, bool BIAS, bool MASK>
__global__ __launch_bounds__(512) void gemm256(
    const _Float16* __restrict__ A, const _Float16* __restrict__ B,
    const float* __restrict__ bias, const int* __restrict__ mask,
    TOUT* __restrict__ Cp, int M, int N, int K, long sA, long sB, long sC) {
  __shared__ _Float16 lds[65536];   // 128 KB
  char* const L = (char*)lds;
  const int tid = threadIdx.x;
  const int w = tid >> 6, l = tid & 63;
  const int l15 = l & 15, q = l >> 4;
  const int wr = (w >> 2) * 128, wc = (w & 3) * 64;

  // ---- XCD-clustered bijective block remap (T1, round-5: FETCH 147->49MB)
  const int gx = gridDim.x, gy = gridDim.y;
  const int nwg = gx * gy * gridDim.z;
  const int lin = (blockIdx.z * gy + blockIdx.y) * gx + blockIdx.x;
  const int li = (lin & 7) * (nwg >> 3) + (lin >> 3);
  const int bx = li % gx;
  const int t1 = li / gx;
  const int by = t1 % gy;
  const int bz = t1 / gy;

  const int m0 = by * 256, n0 = bx * 256;
  const _Float16* Ab = A + (size_t)bz * sA;
  const _Float16* Bb = B + (size_t)bz * sB;

  // stage addressing: per gload round r, thread covers physical byte
  // P = r*8192 + tid*16 of a 16KB half: row = w*16+(l>>2) (+128 for r=1),
  // stored col (l&3)*16; logical col = stored ^ ((row>>1)&3)<<4 ->
  // lane-constant scb, identical for both rounds.
  const int scb = (((l & 3) ^ ((l >> 3) & 3)) << 4);
  const int sr = w * 16 + (l >> 2);
  const long rowB = (long)K * 2;
  const char* aS  = (const char*)Ab + (size_t)(m0 + sr) * rowB + scb;
  const char* aS2 = aS + 128 * rowB;
  const char* bS  = (const char*)Bb + (size_t)(n0 + sr) * rowB + scb;
  const char* bS2 = bS + 128 * rowB;
  const int stW = w * 1024;          // wave-uniform stage dst offset
  // swizzled read col (lane-const): full bank coverage (0 conflicts, r3)
  const int rcb = ((q ^ ((l15 >> 1) & 3)) << 4);
  const int aOff = (wr + l15) * 64 + rcb;           // A: + d*32768 + kk*16384 + m*1024
  const int bOff = 65536 + (wc + l15) * 64 + rcb;   // B: likewise

  f32x4 acc[8][4] = {};
  const int NT = K >> 6;

  // prologue: stage tile 0 (order B-K0, A-K0, A-K1, B-K1) into buf 0
  gload16(bS, L + 65536 + stW);              gload16(bS2, L + 65536 + stW + 8192);
  gload16(aS, L + stW);                      gload16(aS2, L + stW + 8192);
  gload16(aS + 64, L + 16384 + stW);         gload16(aS2 + 64, L + 16384 + stW + 8192);
  gload16(bS + 64, L + 65536 + 16384 + stW); gload16(bS2 + 64, L + 65536 + 16384 + stW + 8192);

  f16x8 af[4], bf[4];

  // main loop: tiles 0..NT-2 (each stages tile t+1; all in-bounds)
  for (int t = 0; t < NT - 1; ++t) {
    const int d = t & 1, dn = d ^ 1, tn = t + 1;
    const char* pAo = L + aOff + dn * 32768;   // buf[d^1]: tile t-1 (kk1)
    const char* pBo = L + bOff + dn * 32768;
    const char* pAc = L + aOff + d * 32768;    // buf[d]:   tile t (kk0)
    const char* pBc = L + bOff + d * 32768;
    char* const sbA = L + dn * 32768 + stW;            // stage dst bases
    const int go = tn * 128;

    // ---- P0: Q3(t-1) ---- reads A-K1 lo + B-K1 (buf dn); stage B-K0(t+1)
    if (t) {
      #pragma unroll
      for (int m = 0; m < 4; m++) af[m] = *(const f16x8*)(pAo + 16384 + m * 1024);
      #pragma unroll
      for (int n = 0; n < 4; n++) bf[n] = *(const f16x8*)(pBo + 16384 + n * 1024);
    }
    gload16(bS + go, sbA + 65536); gload16(bS2 + go, sbA + 65536 + 8192);
    VMCNT(6); BAR(); LGKM0(); SB0();
    if (t) { __builtin_amdgcn_s_setprio(1); G_LO(af, bf); __builtin_amdgcn_s_setprio(0); }
    BAR(); SB0();

    // ---- P1: Q4(t-1) ---- reads A-K1 hi (buf dn); stage A-K0(t+1)
    if (t) {
      #pragma unroll
      for (int m = 0; m < 4; m++) af[m] = *(const f16x8*)(pAo + 16384 + 4096 + m * 1024);
    }
    gload16(aS + go, sbA); gload16(aS2 + go, sbA + 8192);
    VMCNT(6); BAR(); LGKM0(); SB0();
    if (t) { __builtin_amdgcn_s_setprio(1); G_HI(af, bf); __builtin_amdgcn_s_setprio(0); }
    BAR(); SB0();

    // ---- P2: Q1(t) ---- reads A-K0 lo + B-K0 (buf d); stage A-K1(t+1)
    #pragma unroll
    for (int m = 0; m < 4; m++) af[m] = *(const f16x8*)(pAc + m * 1024);
    #pragma unroll
    for (int n = 0; n < 4; n++) bf[n] = *(const f16x8*)(pBc + n * 1024);
    gload16(aS + go + 64, sbA + 16384); gload16(aS2 + go + 64, sbA + 16384 + 8192);
    VMCNT(6); BAR(); LGKM0(); SB0();
    __builtin_amdgcn_s_setprio(1); G_LO(af, bf); __builtin_amdgcn_s_setprio(0);
    BAR(); SB0();

    // ---- P3: Q2(t) ---- reads A-K0 hi (buf d); stage B-K1(t+1)
    #pragma unroll
    for (int m = 0; m < 4; m++) af[m] = *(const f16x8*)(pAc + 4096 + m * 1024);
    gload16(bS + go + 64, sbA + 65536 + 16384); gload16(bS2 + go + 64, sbA + 65536 + 16384 + 8192);
    VMCNT(6); BAR(); LGKM0(); SB0();
    __builtin_amdgcn_s_setprio(1); G_HI(af, bf); __builtin_amdgcn_s_setprio(0);
    BAR(); SB0();
  }

  // final tile t = NT-1 (no stages). vmcnt(4)@P1 retires A-K0; vmcnt(0)@P3
  // retires A-K1/B-K1 for the epilogue quadrants.
  {
    const int d = (NT - 1) & 1, dn = d ^ 1;
    const char* pAo = L + aOff + dn * 32768;
    const char* pBo = L + bOff + dn * 32768;
    const char* pAc = L + aOff + d * 32768;
    const char* pBc = L + bOff + d * 32768;

    // P0: Q3(NT-2)
    #pragma unroll
    for (int m = 0; m < 4; m++) af[m] = *(const f16x8*)(pAo + 16384 + m * 1024);
    #pragma unroll
    for (int n = 0; n < 4; n++) bf[n] = *(const f16x8*)(pBo + 16384 + n * 1024);
    BAR(); LGKM0(); SB0();
    __builtin_amdgcn_s_setprio(1); G_LO(af, bf); __builtin_amdgcn_s_setprio(0);
    BAR(); SB0();
    // P1: Q4(NT-2)
    #pragma unroll
    for (int m = 0; m < 4; m++) af[m] = *(const f16x8*)(pAo + 16384 + 4096 + m * 1024);
    VMCNT(4); BAR(); LGKM0(); SB0();
    __builtin_amdgcn_s_setprio(1); G_HI(af, bf); __builtin_amdgcn_s_setprio(0);
    BAR(); SB0();
    // P2: Q1(NT-1)
    #pragma unroll
    for (int m = 0; m < 4; m++) af[m] = *(const f16x8*)(pAc + m * 1024);
    #pragma unroll
    for (int n = 0; n < 4; n++) bf[n] = *(const f16x8*)(pBc + n * 1024);
    BAR(); LGKM0(); SB0();
    __builtin_amdgcn_s_setprio(1); G_LO(af, bf); __builtin_amdgcn_s_setprio(0);
    BAR(); SB0();
    // P3: Q2(NT-1)
    #pragma unroll
    for (int m = 0; m < 4; m++) af[m] = *(const f16x8*)(pAc + 4096 + m * 1024);
    VMCNT(0); BAR(); LGKM0(); SB0();
    __builtin_amdgcn_s_setprio(1); G_HI(af, bf); __builtin_amdgcn_s_setprio(0);
    BAR(); SB0();
    // epilogue quadrants: Q3/Q4(NT-1) from buf[d]
    #pragma unroll
    for (int m = 0; m < 4; m++) af[m] = *(const f16x8*)(pAc + 16384 + m * 1024);
    #pragma unroll
    for (int n = 0; n < 4; n++) bf[n] = *(const f16x8*)(pBc + 16384 + n * 1024);
    G_LO(af, bf);
    #pragma unroll
    for (int m = 0; m < 4; m++) af[m] = *(const f16x8*)(pAc + 16384 + 4096 + m * 1024);
    G_HI(af, bf);
  }

  TOUT* C = Cp + (size_t)bz * sC;
  const int* Mb = MASK ? (mask + (size_t)bz * ((size_t)M * N)) : nullptr;
  const int q4 = q * 4;
  #pragma unroll
  for (int n = 0; n < 4; n++) {
    int col = n0 + wc + n * 16 + l15;
    float bb = BIAS ? bias[col] : 0.0f;
    #pragma unroll
    for (int m = 0; m < 8; m++) {
      int rowb = m0 + wr + m * 16 + q4;
      #pragma unroll
      for (int rr = 0; rr < 4; rr++) {
        float v = acc[m][n][rr] + bb;
        if constexpr (MASK)
          if (Mb[(size_t)(rowb + rr) * N + col] == 0) v = -60000.0f;
        C[(size_t)(rowb + rr) * N + col] = (TOUT)v;
      }
    }
  }
}

// ---------------------------------------------------------------------------
// fp16 transpose: dst[b][d][m] = src[b][m][d].  64x64 tiles, XOR-swizzled
// 8-half groups -> conflict-free both sides.
// ---------------------------------------------------------------------------
__global__ __launch_bounds__(256) void transpose16_kernel(
    const _Float16* __restrict__ src, _Float16* __restrict__ dst) {
  const int Lm = 2048, D = 1024;
  __shared__ _Float16 tile[64 * 64];
  const int d0 = blockIdx.x * 64, m0 = blockIdx.y * 64;
  const _Float16* s = src + (size_t)blockIdx.z * Lm * D;
  _Float16*       d = dst + (size_t)blockIdx.z * D * Lm;
  const int tid = threadIdx.x;
  #pragma unroll
  for (int it = 0; it < 2; it++) {
    int idx = tid + it * 256;
    int mm = idx >> 3, g = idx & 7;
    int pg = g ^ ((mm >> 3) & 7);
    *(f16x8*)&tile[mm * 64 + pg * 8] =
        *(const f16x8*)&s[(size_t)(m0 + mm) * D + d0 + g * 8];
  }
  __syncthreads();
  #pragma unroll
  for (int it = 0; it < 2; it++) {
    int idx = tid + it * 256;
    int dd = idx >> 3, mc = (idx & 7) * 8;
    f16x8 h;
    #pragma unroll
    for (int j = 0; j < 8; j++) {
      int row = mc + j;
      int pg = (dd >> 3) ^ ((row >> 3) & 7);
      h[j] = tile[row * 64 + pg * 8 + (dd & 7)];
    }
    *(f16x8*)&d[(size_t)(d0 + dd) * Lm + m0 + mc] = h;
  }
}

// ---------------------------------------------------------------------------
// softmax in place over PRE-MASKED fp16 logits (mask applied in the scores
// epilogue as -60000 sentinel -> exp == 0.0f exactly, same as reference's
// logit-1e6 path).  One block per (b,q) row.  No mask read (saves 128 MB).
// ---------------------------------------------------------------------------
__global__ __launch_bounds__(256) void softmax_kernel(_Float16* __restrict__ wbuf) {
  const int Lm = 2048;
  size_t row = blockIdx.x;
  _Float16* wr = wbuf + row * Lm;
  int tid = threadIdx.x;
  f16x8 lv = *(const f16x8*)&wr[tid * 8];
  float v[8];
  float mx = -3.0e38f;
  #pragma unroll
  for (int i = 0; i < 8; i++) {
    v[i] = (float)lv[i];
    mx = fmaxf(mx, v[i]);
  }
  #pragma unroll
  for (int off = 32; off > 0; off >>= 1) mx = fmaxf(mx, __shfl_down(mx, off, 64));
  __shared__ float red[4];
  int wv = tid >> 6;
  if ((tid & 63) == 0) red[wv] = mx;
  __syncthreads();
  mx = fmaxf(fmaxf(red[0], red[1]), fmaxf(red[2], red[3]));
  __syncthreads();
  float s = 0.f;
  #pragma unroll
  for (int i = 0; i < 8; i++) { v[i] = __expf(v[i] - mx); s += v[i]; }
  #pragma unroll
  for (int off = 32; off > 0; off >>= 1) s += __shfl_down(s, off, 64);
  if ((tid & 63) == 0) red[wv] = s;
  __syncthreads();
  float inv = 1.0f / (red[0] + red[1] + red[2] + red[3]);
  f16x8 o;
  #pragma unroll
  for (int i = 0; i < 8; i++) o[i] = (_Float16)(v[i] * inv);
  *(f16x8*)&wr[tid * 8] = o;
}

// ---------------------------------------------------------------------------
// fp32 -> fp16 convert, 8 elems/thread
// ---------------------------------------------------------------------------
__global__ __launch_bounds__(256) void cvt8_kernel(const float* __restrict__ x,
                                                   _Float16* __restrict__ y) {
  size_t i = (size_t)(blockIdx.x * 256 + threadIdx.x) * 8;
  f32x4 a = *(const f32x4*)&x[i];
  f32x4 b = *(const f32x4*)&x[i + 4];
  f16x8 h = {(_Float16)a[0], (_Float16)a[1], (_Float16)a[2], (_Float16)a[3],
             (_Float16)b[0], (_Float16)b[1], (_Float16)b[2], (_Float16)b[3]};
  *(f16x8*)&y[i] = h;
}

// ---------------------------------------------------------------------------
// B=8, Lq=Lm=2048, Din=Dout=1024
//
// buffer plan (ws = 96 MB, d_out = 64 MB used as scratch before pv):
//   ws[0,32M):   qproj fp16 [16384,1024] (proj -> scores);
//                then memT fp16 [B,1024,2048] overwrites it (after scores)
//   ws[32M,64M): queryh fp16 (transient, dead after proj)
//   ws[64M,66M): Wh fp16     (transient, dead after proj)
//   ws[32M,96M): wbuf fp16 [B,Lq,Lm] (masked logits -> softmax -> weights)
//   d_out[0,32M): memh fp16 (cvt of mem; dead before pv writes out)
//
// BUGFIX (kept): pv's output batch stride is LQK (out is [B,2048,1024]).
// ---------------------------------------------------------------------------
extern "C" void kernel_launch(void* const* d_in, const int* in_sizes, int n_in,
                              void* d_out, int out_size, void* d_ws, size_t ws_size,
                              hipStream_t stream) {
  const float* query = (const float*)d_in[0];
  const float* mem   = (const float*)d_in[1];
  const int*   mask  = (const int*)d_in[2];
  const float* W     = (const float*)d_in[3];
  const float* bias  = (const float*)d_in[4];
  float* out = (float*)d_out;

  char* ws = (char*)d_ws;
  _Float16* qproj  = (_Float16*)ws;                                // 32 MB
  _Float16* memT   = (_Float16*)ws;                                // aliases qproj
  _Float16* queryh = (_Float16*)(ws + (size_t)32 * 1024 * 1024);   // transient
  _Float16* Wh     = (_Float16*)(ws + (size_t)64 * 1024 * 1024);   // transient
  _Float16* wbuf   = (_Float16*)(ws + (size_t)32 * 1024 * 1024);   // 64 MB
  _Float16* memh   = (_Float16*)d_out;                             // 32 MB scratch

  const long LQK = 2048L * 1024, LQM = 2048L * 2048;

  // fp32 -> fp16 pre-passes
  cvt8_kernel<<<dim3(512),  256, 0, stream>>>(W, Wh);
  cvt8_kernel<<<dim3(8192), 256, 0, stream>>>(query, queryh);
  cvt8_kernel<<<dim3(8192), 256, 0, stream>>>(mem, memh);
  // proj: qproj[16384,1024] = queryh * Wh^T + b  (nwg=256, %8==0)
  gemm256<_Float16, true, false><<<dim3(4, 64, 1), 512, 0, stream>>>(
      queryh, Wh, bias, nullptr, qproj, 16384, 1024, 1024, 0, 0, 0);
  // scores: wbuf[b][2048,2048] = qproj * memh^T, mask fused into epilogue
  gemm256<_Float16, false, true><<<dim3(8, 8, 8), 512, 0, stream>>>(
      qproj, memh, nullptr, mask, wbuf, 2048, 2048, 1024, LQK, LQK, LQM);
  // softmax in place (no mask read -- already applied)
  softmax_kernel<<<dim3(16384), 256, 0, stream>>>(wbuf);
  // memT[b][1024,2048] = memh^T   (qproj dead -> reuse its space)
  transpose16_kernel<<<dim3(16, 32, 8), 256, 0, stream>>>(memh, memT);
  // pv: out[b][2048,1024] = wbuf * memT^T  (nwg=256: 1 batch per XCD; sC=LQK)
  gemm256<float, false, false><<<dim3(4, 8, 8), 512, 0, stream>>>(
      wbuf, memT, nullptr, nullptr, out, 2048, 1024, 2048, LQM, LQK, LQK);
}

// Round 7
// 477.860 us; speedup vs baseline: 1.2140x; 1.2140x over previous
//
#include <hip/hip_runtime.h>

typedef float    f32x4 __attribute__((ext_vector_type(4)));
typedef _Float16 f16x4 __attribute__((ext_vector_type(4)));
typedef _Float16 f16x8 __attribute__((ext_vector_type(8)));

// direct global->LDS DMA, 16B per lane. LDS dest is wave-uniform base;
// HW writes lane l at (ldsbase + l*16). Global src is per-lane.
__device__ __forceinline__ void gload16(const void* g, void* l) {
  __builtin_amdgcn_global_load_lds(
      (const __attribute__((address_space(1))) void*)g,
      (__attribute__((address_space(3))) void*)l, 16, 0, 0);
}

#define MFMA16(d, a, b) __builtin_amdgcn_mfma_f32_16x16x32_f16(a, b, d, 0, 0, 0)
#define VMCNT0() asm volatile("s_waitcnt vmcnt(0)" ::: "memory")
#define BAR()    __builtin_amdgcn_s_barrier()

// ---------------------------------------------------------------------------
// 256x128 fp16 GEMM, C = A * B^T (+bias), fp32 accum.  BK=32.
// 512 thr = 8 waves as 4M x 2N; per-wave C = 64x64, acc[4][4] f32x4 (64 regs).
// LDS = 48 KB: A[2][256][32]h @0, B[2][128][32]h @32768.  With
// __launch_bounds__(512,4) -> <=128 VGPR -> TWO blocks resident per CU:
// one block's MFMA window overlaps the other's DS/stage window (m114
// cross-block overlap), which intra-block scheduling could not achieve at
// 1 block/CU (rounds 2-6: five schedules, all ~same).
//
// Layout per K-half: [rows][32 halfs], 64B rows; XOR swizzle
// col ^= ((row>>1)&3)<<4 via pre-swizzled GLOBAL source (linear DMA dest) +
// swizzled ds_read col (verified conflicts = 0, round 3).
//
// Per tile t (buf d=t&1): issue 3 DMAs for t+1 into buf[d^1]; read
// af[4]+bf[4] (8 x ds_read_b128); 16 MFMA; vmcnt(0); s_barrier.
// Accumulation: ascending K in 32-chunks, one MFMA per acc element per
// tile -> bit-identical to prior rounds' per-element sum order.
// ---------------------------------------------------------------------------
template <typename TOUT, bool BIAS>
__global__ __launch_bounds__(512, 4) void gemm256x128(
    const _Float16* __restrict__ A, const _Float16* __restrict__ B,
    const float* __restrict__ bias, TOUT* __restrict__ Cp,
    int M, int N, int K, long sA, long sB, long sC) {
  __shared__ _Float16 lds[24576];   // 48 KB
  char* const L = (char*)lds;
  const int tid = threadIdx.x;
  const int w = tid >> 6, l = tid & 63;
  const int l15 = l & 15, q = l >> 4;
  const int wr = (w >> 1) * 64, wc = (w & 1) * 64;

  // ---- XCD-clustered bijective block remap (T1; FETCH 147->49MB, r5).
  // x-innermost decomposition => each XCD owns whole batches (L2-resident
  // panels). All grids here have nwg % 8 == 0.
  const int gx = gridDim.x, gy = gridDim.y;
  const int nwg = gx * gy * gridDim.z;
  const int lin = (blockIdx.z * gy + blockIdx.y) * gx + blockIdx.x;
  const int li = (lin & 7) * (nwg >> 3) + (lin >> 3);
  const int bx = li % gx;
  const int t1 = li / gx;
  const int by = t1 % gy;
  const int bz = t1 / gy;

  const int m0 = by * 256, n0 = bx * 128;
  const _Float16* Ab = A + (size_t)bz * sA;
  const _Float16* Bb = B + (size_t)bz * sB;

  // stage addressing: gload round covers physical bytes tid*16 of an 8KB
  // half-rowset: row = w*16 + (l>>2), stored col (l&3)*16; logical col =
  // stored ^ ((row>>1)&3)<<4 -> lane-constant scb.
  const int scb = (((l & 3) ^ ((l >> 3) & 3)) << 4);
  const int sr = w * 16 + (l >> 2);            // 0..127
  const long rowB = (long)K * 2;
  const char* aS  = (const char*)Ab + (size_t)(m0 + sr) * rowB + scb;
  const char* aS2 = aS + 128 * rowB;           // A rows 128..255
  const char* bS  = (const char*)Bb + (size_t)(n0 + sr) * rowB + scb;
  const int stW = w * 1024;                    // wave-uniform stage offset
  // swizzled read col (lane-const): full bank coverage (0 conflicts, r3)
  const int rcb = ((q ^ ((l15 >> 1) & 3)) << 4);
  const int aOff = (wr + l15) * 64 + rcb;          // + d*16384 + m*1024
  const int bOff = 32768 + (wc + l15) * 64 + rcb;  // + d*8192  + n*1024

  f32x4 acc[4][4] = {};
  const int NT = K >> 5;                       // BK = 32

  // prologue: stage tile 0 into buf 0 (A: 2 rounds, B: 1 round)
  gload16(aS, L + stW);
  gload16(aS2, L + stW + 8192);
  gload16(bS, L + 32768 + stW);
  VMCNT0();
  BAR();

  for (int t = 0; t < NT - 1; ++t) {
    const int d = t & 1, dn = d ^ 1;
    const long go = (long)(t + 1) * 64;        // next tile's K byte offset
    // issue DMAs for tile t+1 (overlap under this tile's DS+MFMA, and
    // under the co-resident block's work)
    char* sbA = L + dn * 16384 + stW;
    char* sbB = L + 32768 + dn * 8192 + stW;
    gload16(aS + go, sbA);
    gload16(aS2 + go, sbA + 8192);
    gload16(bS + go, sbB);

    const char* pA = L + d * 16384 + aOff;
    const char* pB = L + d * 8192 + bOff;
    f16x8 af[4], bf[4];
    #pragma unroll
    for (int m = 0; m < 4; m++) af[m] = *(const f16x8*)(pA + m * 1024);
    #pragma unroll
    for (int n = 0; n < 4; n++) bf[n] = *(const f16x8*)(pB + n * 1024);

    __builtin_amdgcn_s_setprio(1);
    #pragma unroll
    for (int m = 0; m < 4; m++)
      #pragma unroll
      for (int n = 0; n < 4; n++)
        acc[m][n] = MFMA16(acc[m][n], af[m], bf[n]);
    __builtin_amdgcn_s_setprio(0);

    VMCNT0();          // t+1 DMAs landed (issued a full tile ago)
    BAR();             // publish; also retires all tile-t ds_reads
  }

  // final tile (no staging)
  {
    const int d = (NT - 1) & 1;
    const char* pA = L + d * 16384 + aOff;
    const char* pB = L + d * 8192 + bOff;
    f16x8 af[4], bf[4];
    #pragma unroll
    for (int m = 0; m < 4; m++) af[m] = *(const f16x8*)(pA + m * 1024);
    #pragma unroll
    for (int n = 0; n < 4; n++) bf[n] = *(const f16x8*)(pB + n * 1024);
    #pragma unroll
    for (int m = 0; m < 4; m++)
      #pragma unroll
      for (int n = 0; n < 4; n++)
        acc[m][n] = MFMA16(acc[m][n], af[m], bf[n]);
  }

  TOUT* C = Cp + (size_t)bz * sC;
  const int q4 = q * 4;
  #pragma unroll
  for (int n = 0; n < 4; n++) {
    int col = n0 + wc + n * 16 + l15;
    float bb = BIAS ? bias[col] : 0.0f;
    #pragma unroll
    for (int m = 0; m < 4; m++) {
      int rowb = m0 + wr + m * 16 + q4;
      #pragma unroll
      for (int rr = 0; rr < 4; rr++)
        C[(size_t)(rowb + rr) * N + col] = (TOUT)(acc[m][n][rr] + bb);
    }
  }
}

// ---------------------------------------------------------------------------
// fp16 transpose: dst[b][d][m] = src[b][m][d].  64x64 tiles, XOR-swizzled
// 8-half groups -> conflict-free both sides.
// ---------------------------------------------------------------------------
__global__ __launch_bounds__(256) void transpose16_kernel(
    const _Float16* __restrict__ src, _Float16* __restrict__ dst) {
  const int Lm = 2048, D = 1024;
  __shared__ _Float16 tile[64 * 64];
  const int d0 = blockIdx.x * 64, m0 = blockIdx.y * 64;
  const _Float16* s = src + (size_t)blockIdx.z * Lm * D;
  _Float16*       d = dst + (size_t)blockIdx.z * D * Lm;
  const int tid = threadIdx.x;
  #pragma unroll
  for (int it = 0; it < 2; it++) {
    int idx = tid + it * 256;
    int mm = idx >> 3, g = idx & 7;
    int pg = g ^ ((mm >> 3) & 7);
    *(f16x8*)&tile[mm * 64 + pg * 8] =
        *(const f16x8*)&s[(size_t)(m0 + mm) * D + d0 + g * 8];
  }
  __syncthreads();
  #pragma unroll
  for (int it = 0; it < 2; it++) {
    int idx = tid + it * 256;
    int dd = idx >> 3, mc = (idx & 7) * 8;
    f16x8 h;
    #pragma unroll
    for (int j = 0; j < 8; j++) {
      int row = mc + j;
      int pg = (dd >> 3) ^ ((row >> 3) & 7);
      h[j] = tile[row * 64 + pg * 8 + (dd & 7)];
    }
    *(f16x8*)&d[(size_t)(d0 + dd) * Lm + m0 + mc] = h;
  }
}

// ---------------------------------------------------------------------------
// per-row mask + softmax in place over fp16 logits; one block per (b,q) row
// (round-5 version: mask applied here, where its 128 MB read streams at
// full BW instead of serializing in a GEMM epilogue -- round-6 lesson)
// ---------------------------------------------------------------------------
__global__ __launch_bounds__(256) void softmax_kernel(
    const int* __restrict__ mask, _Float16* __restrict__ wbuf) {
  const int Lm = 2048;
  size_t row = blockIdx.x;
  _Float16* wr = wbuf + row * Lm;
  const int* mr = mask + row * Lm;
  int tid = threadIdx.x;
  f16x8 lv = *(const f16x8*)&wr[tid * 8];
  int4 ma = *(const int4*)&mr[tid * 8];
  int4 mb = *(const int4*)&mr[tid * 8 + 4];
  int mk[8] = {ma.x, ma.y, ma.z, ma.w, mb.x, mb.y, mb.z, mb.w};
  float v[8];
  float mx = -3.0e38f;
  #pragma unroll
  for (int i = 0; i < 8; i++) {
    float l = (float)lv[i];
    if (mk[i] == 0) l += -1000000.0f;
    v[i] = l;
    mx = fmaxf(mx, l);
  }
  #pragma unroll
  for (int off = 32; off > 0; off >>= 1) mx = fmaxf(mx, __shfl_down(mx, off, 64));
  __shared__ float red[4];
  int wv = tid >> 6;
  if ((tid & 63) == 0) red[wv] = mx;
  __syncthreads();
  mx = fmaxf(fmaxf(red[0], red[1]), fmaxf(red[2], red[3]));
  __syncthreads();
  float s = 0.f;
  #pragma unroll
  for (int i = 0; i < 8; i++) { v[i] = __expf(v[i] - mx); s += v[i]; }
  #pragma unroll
  for (int off = 32; off > 0; off >>= 1) s += __shfl_down(s, off, 64);
  if ((tid & 63) == 0) red[wv] = s;
  __syncthreads();
  float inv = 1.0f / (red[0] + red[1] + red[2] + red[3]);
  f16x8 o;
  #pragma unroll
  for (int i = 0; i < 8; i++) o[i] = (_Float16)(v[i] * inv);
  *(f16x8*)&wr[tid * 8] = o;
}

// ---------------------------------------------------------------------------
// fp32 -> fp16 convert, 8 elems/thread
// ---------------------------------------------------------------------------
__global__ __launch_bounds__(256) void cvt8_kernel(const float* __restrict__ x,
                                                   _Float16* __restrict__ y) {
  size_t i = (size_t)(blockIdx.x * 256 + threadIdx.x) * 8;
  f32x4 a = *(const f32x4*)&x[i];
  f32x4 b = *(const f32x4*)&x[i + 4];
  f16x8 h = {(_Float16)a[0], (_Float16)a[1], (_Float16)a[2], (_Float16)a[3],
             (_Float16)b[0], (_Float16)b[1], (_Float16)b[2], (_Float16)b[3]};
  *(f16x8*)&y[i] = h;
}

// ---------------------------------------------------------------------------
// B=8, Lq=Lm=2048, Din=Dout=1024
//
// buffer plan (ws = 96 MB, d_out = 64 MB used as scratch before pv):
//   ws[0,32M):   qproj fp16 [16384,1024] (proj -> scores);
//                then memT fp16 [B,1024,2048] overwrites it (after scores)
//   ws[32M,64M): queryh fp16 (transient, dead after proj)
//   ws[64M,66M): Wh fp16     (transient, dead after proj)
//   ws[32M,96M): wbuf fp16 [B,Lq,Lm] (logits -> mask+softmax -> weights)
//   d_out[0,32M): memh fp16 (cvt of mem; dead before pv writes out)
//
// BUGFIX (kept): pv's output batch stride is LQK (out is [B,2048,1024]).
// ---------------------------------------------------------------------------
extern "C" void kernel_launch(void* const* d_in, const int* in_sizes, int n_in,
                              void* d_out, int out_size, void* d_ws, size_t ws_size,
                              hipStream_t stream) {
  const float* query = (const float*)d_in[0];
  const float* mem   = (const float*)d_in[1];
  const int*   mask  = (const int*)d_in[2];
  const float* W     = (const float*)d_in[3];
  const float* bias  = (const float*)d_in[4];
  float* out = (float*)d_out;

  char* ws = (char*)d_ws;
  _Float16* qproj  = (_Float16*)ws;                                // 32 MB
  _Float16* memT   = (_Float16*)ws;                                // aliases qproj
  _Float16* queryh = (_Float16*)(ws + (size_t)32 * 1024 * 1024);   // transient
  _Float16* Wh     = (_Float16*)(ws + (size_t)64 * 1024 * 1024);   // transient
  _Float16* wbuf   = (_Float16*)(ws + (size_t)32 * 1024 * 1024);   // 64 MB
  _Float16* memh   = (_Float16*)d_out;                             // 32 MB scratch

  const long LQK = 2048L * 1024, LQM = 2048L * 2048;

  // fp32 -> fp16 pre-passes
  cvt8_kernel<<<dim3(512),  256, 0, stream>>>(W, Wh);
  cvt8_kernel<<<dim3(8192), 256, 0, stream>>>(query, queryh);
  cvt8_kernel<<<dim3(8192), 256, 0, stream>>>(mem, memh);
  // proj: qproj[16384,1024] = queryh * Wh^T + b  (nwg=512, 2 blocks/CU)
  gemm256x128<_Float16, true><<<dim3(8, 64, 1), 512, 0, stream>>>(
      queryh, Wh, bias, qproj, 16384, 1024, 1024, 0, 0, 0);
  // scores: wbuf[b][2048,2048] = qproj * memh^T  (nwg=1024)
  gemm256x128<_Float16, false><<<dim3(16, 8, 8), 512, 0, stream>>>(
      qproj, memh, nullptr, wbuf, 2048, 2048, 1024, LQK, LQK, LQM);
  // mask + softmax in place
  softmax_kernel<<<dim3(16384), 256, 0, stream>>>(mask, wbuf);
  // memT[b][1024,2048] = memh^T   (qproj dead -> reuse its space)
  transpose16_kernel<<<dim3(16, 32, 8), 256, 0, stream>>>(memh, memT);
  // pv: out[b][2048,1024] = wbuf * memT^T  (nwg=512; sC = LQK, NOT LQM!)
  gemm256x128<float, false><<<dim3(8, 8, 8), 512, 0, stream>>>(
      wbuf, memT, nullptr, out, 2048, 1024, 2048, LQM, LQK, LQK);
}